// Round 1
// baseline (489.181 us; speedup 1.0000x reference)
//
#include <hip/hip_runtime.h>

#define MAXN 128

__global__ __launch_bounds__(256) void greens_kernel(
    const float* __restrict__ he,    // (B, N)
    const float* __restrict__ h0d,   // (N)
    const float* __restrict__ h0sub, // (N-1)
    const float* __restrict__ h0sup, // (N-1)
    float2* __restrict__ out,        // (B, N) complex; reused as theta scratch
    int Bn, int N)
{
    __shared__ float sa[MAXN];   // h0_diag
    __shared__ float sbc[MAXN];  // h0_super * h0_sub
    const int t = threadIdx.x;
    if (t < N)     sa[t]  = h0d[t];
    if (t < N - 1) sbc[t] = h0sub[t] * h0sup[t];
    __syncthreads();

    const int b = blockIdx.x * blockDim.x + t;
    if (b >= Bn) return;

    const float* __restrict__ row  = he  + (size_t)b * N;
    float2*      __restrict__ orow = out + (size_t)b * N;

    // ---- forward continuant: theta_0..theta_N, store theta_0..theta_{N-1} ----
    // theta_0 = 1, theta_1 = a_0 - i
    // theta_{k+1} = (a_k - i) theta_k - bc_{k-1} theta_{k-1}
    double tpr = 1.0, tpi = 0.0;                       // theta_{k-1}
    double tcr = (double)sa[0] + (double)row[0];       // theta_k (k=1)
    double tci = -1.0;
    orow[0] = make_float2(1.0f, 0.0f);
    #pragma unroll 4
    for (int k = 1; k < N; ++k) {
        orow[k] = make_float2((float)tcr, (float)tci);
        double ak = (double)sa[k] + (double)row[k];
        double bk = (double)sbc[k - 1];
        double nr = fma(ak, tcr,  tci) - bk * tpr;
        double ni = fma(ak, tci, -tcr) - bk * tpi;
        tpr = tcr; tpi = tci; tcr = nr; tci = ni;
    }
    // tcr,tci = theta_N = denominator
    const double dr = tcr, di = tci;
    const double inv = 1.0 / (dr * dr + di * di);
    const double cr  =  dr * inv;   // 1/den = conj(den)*inv
    const double ci_ = -di * inv;

    // ---- backward continuant: phi_j = (a_j - i) phi_{j+1} - bc_j phi_{j+2} ----
    // phi_N = 1 (phi_{N+1} = 0). At iter j, f1 = phi_{j+1}, f2 = phi_{j+2}.
    double f1r = 1.0, f1i = 0.0;
    double f2r = 0.0, f2i = 0.0;
    #pragma unroll 4
    for (int j = N - 1; j >= 0; --j) {
        float2 th = orow[j];
        double tr = (double)th.x, ti = (double)th.y;
        // num_j = theta_j * phi_{j+1}
        double nr = tr * f1r - ti * f1i;
        double ni = tr * f1i + ti * f1r;
        // G_j = num_j / den
        double gr = nr * cr - ni * ci_;
        double gi = nr * ci_ + ni * cr;
        orow[j] = make_float2((float)gr, (float)gi);
        // phi_j
        double aj = (double)sa[j] + (double)row[j];
        double bj = (j < N - 1) ? (double)sbc[j] : 0.0;
        double pr = fma(aj, f1r,  f1i) - bj * f2r;
        double pi = fma(aj, f1i, -f1r) - bj * f2i;
        f2r = f1r; f2i = f1i; f1r = pr; f1i = pi;
    }
}

extern "C" void kernel_launch(void* const* d_in, const int* in_sizes, int n_in,
                              void* d_out, int out_size, void* d_ws, size_t ws_size,
                              hipStream_t stream) {
    const float* he    = (const float*)d_in[0];
    const float* h0d   = (const float*)d_in[1];
    const float* h0sub = (const float*)d_in[2];
    const float* h0sup = (const float*)d_in[3];
    const int N  = in_sizes[1];           // 80
    const int Bn = in_sizes[0] / N;       // 131072
    float2* out = (float2*)d_out;

    const int block = 256;
    const int grid  = (Bn + block - 1) / block;
    hipLaunchKernelGGL(greens_kernel, dim3(grid), dim3(block), 0, stream,
                       he, h0d, h0sub, h0sup, out, Bn, N);
}

// Round 2
// 139.893 us; speedup vs baseline: 3.4968x; 3.4968x over previous
//
#include <hip/hip_runtime.h>

#define MAXN 128

// ================= optimized path: compile-time N, 256 rows/block =============
template<int N>
__global__ __launch_bounds__(256, 2) void greens_opt(
    const float* __restrict__ he,    // (B, N)
    const float* __restrict__ h0d,   // (N)
    const float* __restrict__ h0sub, // (N-1)
    const float* __restrict__ h0sup, // (N-1)
    float2* __restrict__ out)        // (B, N) complex
{
    constexpr int ROWS  = 256;
    constexpr int CHUNK = 16;
    static_assert(N % CHUNK == 0, "N must be multiple of 16");

    __shared__ float  sA[CHUNK][ROWS + 1];   // a-values, transposed chunk
    __shared__ float2 sO[CHUNK][ROWS + 1];   // G-values, transposed chunk
    __shared__ float  sd[N];                 // h0_diag
    __shared__ float  sB[N];                 // bc (sB[N-1] = 0)

    const int t = threadIdx.x;
    if (t < N)     sd[t] = h0d[t];
    if (t < N - 1) sB[t] = h0sub[t] * h0sup[t];
    if (t == N - 1) sB[t] = 0.0f;
    __syncthreads();

    const int row0 = blockIdx.x * ROWS;
    const float* __restrict__ tile  = he  + (size_t)row0 * N;
    float2*      __restrict__ otile = out + (size_t)row0 * N;

    // Stage chunk c of a = h0_diag + he into sA (transposed), coalesced float4.
    auto stageA = [&](int c) {
        #pragma unroll
        for (int i = 0; i < (ROWS * CHUNK / 4) / 256; ++i) {   // 4 iters
            int f4  = i * 256 + t;        // float4 index within chunk
            int r   = f4 >> 2;            // row in tile
            int kkb = (f4 & 3) << 2;      // col-in-chunk base
            const float4 v = *(const float4*)(tile + (size_t)r * N + c * CHUNK + kkb);
            sA[kkb + 0][r] = v.x + sd[c * CHUNK + kkb + 0];
            sA[kkb + 1][r] = v.y + sd[c * CHUNK + kkb + 1];
            sA[kkb + 2][r] = v.z + sd[c * CHUNK + kkb + 2];
            sA[kkb + 3][r] = v.w + sd[c * CHUNK + kkb + 3];
        }
    };

    // Flush chunk c of G from sO to out, coalesced float4 (2 complex per store).
    auto flushO = [&](int c) {
        #pragma unroll
        for (int i = 0; i < (ROWS * CHUNK / 2) / 256; ++i) {   // 8 iters
            int f4 = i * 256 + t;         // float4 index = 2 float2
            int r  = f4 >> 3;
            int kk = (f4 & 7) << 1;
            float2 g0 = sO[kk][r];
            float2 g1 = sO[kk + 1][r];
            float4 v  = make_float4(g0.x, g0.y, g1.x, g1.y);
            *(float4*)(otile + (size_t)r * N + c * CHUNK + kk) = v;
        }
    };

    // ---------------- forward continuant, theta in registers ----------------
    float2 th[N];
    stageA(0);
    __syncthreads();

    double tpr = 1.0, tpi = 0.0;                       // theta_0
    double tcr = (double)sA[0][t], tci = -1.0;         // theta_1
    th[0] = make_float2(1.0f, 0.0f);

    #pragma unroll
    for (int k = 1; k < N; ++k) {
        if ((k & (CHUNK - 1)) == 0) {
            __syncthreads();
            stageA(k >> 4);
            __syncthreads();
        }
        th[k] = make_float2((float)tcr, (float)tci);
        double ak = (double)sA[k & (CHUNK - 1)][t];
        double bk = (double)sB[k - 1];
        double nr = fma(ak, tcr,  tci) - bk * tpr;
        double ni = fma(ak, tci, -tcr) - bk * tpi;
        tpr = tcr; tpi = tci; tcr = nr; tci = ni;
    }
    // theta_N = denominator; 1/den = conj(den) * inv|den|^2
    const double dr = tcr, di = tci;
    const double inv = 1.0 / (dr * dr + di * di);
    const double cr  =  dr * inv;
    const double ci  = -di * inv;

    // ---------------- backward continuant + epilogue ----------------
    double f1r = 1.0, f1i = 0.0;   // phi_{j+1}
    double f2r = 0.0, f2i = 0.0;   // phi_{j+2}
    #pragma unroll
    for (int j = N - 1; j >= 0; --j) {
        if ((j & (CHUNK - 1)) == (CHUNK - 1)) {
            __syncthreads();
            stageA(j >> 4);
            __syncthreads();
        }
        float2 thj = th[j];
        double tr = (double)thj.x, ti = (double)thj.y;
        double nr = tr * f1r - ti * f1i;
        double ni = tr * f1i + ti * f1r;
        sO[j & (CHUNK - 1)][t] =
            make_float2((float)(nr * cr - ni * ci), (float)(nr * ci + ni * cr));
        double aj = (double)sA[j & (CHUNK - 1)][t];
        double bj = (double)sB[j];
        double pr = fma(aj, f1r,  f1i) - bj * f2r;
        double pi = fma(aj, f1i, -f1r) - bj * f2i;
        f2r = f1r; f2i = f1i; f1r = pr; f1i = pi;
        if ((j & (CHUNK - 1)) == 0) {
            __syncthreads();
            flushO(j >> 4);
        }
    }
}

// ================= generic fallback (round-1 kernel) =========================
__global__ __launch_bounds__(256) void greens_generic(
    const float* __restrict__ he,
    const float* __restrict__ h0d,
    const float* __restrict__ h0sub,
    const float* __restrict__ h0sup,
    float2* __restrict__ out,
    int Bn, int N)
{
    __shared__ float sa[MAXN];
    __shared__ float sbc[MAXN];
    const int t = threadIdx.x;
    if (t < N)     sa[t]  = h0d[t];
    if (t < N - 1) sbc[t] = h0sub[t] * h0sup[t];
    __syncthreads();

    const int b = blockIdx.x * blockDim.x + t;
    if (b >= Bn) return;

    const float* __restrict__ row  = he  + (size_t)b * N;
    float2*      __restrict__ orow = out + (size_t)b * N;

    double tpr = 1.0, tpi = 0.0;
    double tcr = (double)sa[0] + (double)row[0];
    double tci = -1.0;
    orow[0] = make_float2(1.0f, 0.0f);
    for (int k = 1; k < N; ++k) {
        orow[k] = make_float2((float)tcr, (float)tci);
        double ak = (double)sa[k] + (double)row[k];
        double bk = (double)sbc[k - 1];
        double nr = fma(ak, tcr,  tci) - bk * tpr;
        double ni = fma(ak, tci, -tcr) - bk * tpi;
        tpr = tcr; tpi = tci; tcr = nr; tci = ni;
    }
    const double dr = tcr, di = tci;
    const double inv = 1.0 / (dr * dr + di * di);
    const double cr  =  dr * inv;
    const double ci_ = -di * inv;

    double f1r = 1.0, f1i = 0.0;
    double f2r = 0.0, f2i = 0.0;
    for (int j = N - 1; j >= 0; --j) {
        float2 thv = orow[j];
        double tr = (double)thv.x, ti = (double)thv.y;
        double nr = tr * f1r - ti * f1i;
        double ni = tr * f1i + ti * f1r;
        double gr = nr * cr - ni * ci_;
        double gi = nr * ci_ + ni * cr;
        orow[j] = make_float2((float)gr, (float)gi);
        double aj = (double)sa[j] + (double)row[j];
        double bj = (j < N - 1) ? (double)sbc[j] : 0.0;
        double pr = fma(aj, f1r,  f1i) - bj * f2r;
        double pi = fma(aj, f1i, -f1r) - bj * f2i;
        f2r = f1r; f2i = f1i; f1r = pr; f1i = pi;
    }
}

extern "C" void kernel_launch(void* const* d_in, const int* in_sizes, int n_in,
                              void* d_out, int out_size, void* d_ws, size_t ws_size,
                              hipStream_t stream) {
    const float* he    = (const float*)d_in[0];
    const float* h0d   = (const float*)d_in[1];
    const float* h0sub = (const float*)d_in[2];
    const float* h0sup = (const float*)d_in[3];
    const int N  = in_sizes[1];           // 80
    const int Bn = in_sizes[0] / N;       // 131072
    float2* out = (float2*)d_out;

    if (N == 80 && (Bn % 256) == 0) {
        const int grid = Bn / 256;
        hipLaunchKernelGGL((greens_opt<80>), dim3(grid), dim3(256), 0, stream,
                           he, h0d, h0sub, h0sup, out);
    } else {
        const int block = 256;
        const int grid  = (Bn + block - 1) / block;
        hipLaunchKernelGGL(greens_generic, dim3(grid), dim3(block), 0, stream,
                           he, h0d, h0sub, h0sup, out, Bn, N);
    }
}

// Round 3
// 127.321 us; speedup vs baseline: 3.8421x; 1.0987x over previous
//
#include <hip/hip_runtime.h>

#define MAXN 128

// ============ continued-fraction kernel: 2 threads/row, fp32, N=80 ===========
// 1/G_j = d_j - e_j - c_j,  e_j = bc_{j-1}/F_{j-1},  c_j = bc_j/W_{j+1}
// F_j = d_j - e_j (fwd ratio theta_{j+1}/theta_j), W_j = d_j - c_j (bwd ratio
// phi_j/phi_{j+1}). Im(F),Im(W) <= -1 so everything is O(1) and fp32-stable.
template<int N>
__global__ __launch_bounds__(128, 4) void greens_cf(
    const float* __restrict__ he,    // (B, N)
    const float* __restrict__ h0d,   // (N)
    const float* __restrict__ h0sub, // (N-1)
    const float* __restrict__ h0sup, // (N-1)
    float2* __restrict__ out)        // (B, N)
{
    constexpr int ROWS = 64;
    constexpr int MID  = N / 2;      // 40
    static_assert(N == 80, "tuned for N=80");

    __shared__ float  sA[ROWS][N + 1];   // a = h0d + he, padded (bank-safe)
    __shared__ float2 sO[ROWS][17];      // out staging: cols 0-7 A, 8-15 B
    __shared__ float2 sFb[ROWS];         // F_{MID-1} handoff A->B
    __shared__ float2 sWb[ROWS];         // W_MID handoff B->A
    __shared__ float  sBC[N];            // bc_j = h0sub[j]*h0sup[j]

    const int t = threadIdx.x;
    if (t < N - 1) sBC[t] = h0sub[t] * h0sup[t];

    const int row0 = blockIdx.x * ROWS;
    const float* __restrict__ tile  = he  + (size_t)row0 * N;
    float2*      __restrict__ otile = out + (size_t)row0 * N;

    // ---- stage a-tile (coalesced float4), pre-adding h0_diag ----
    #pragma unroll
    for (int i = 0; i < (ROWS * N / 4) / 128; ++i) {     // 10 iters
        int idx = i * 128 + t;
        int rr  = idx / (N / 4);
        int q   = idx - rr * (N / 4);
        int col = q * 4;
        float4 v  = *(const float4*)(tile + (size_t)rr * N + col);
        float4 dv = *(const float4*)(h0d + col);
        sA[rr][col + 0] = v.x + dv.x;
        sA[rr][col + 1] = v.y + dv.y;
        sA[rr][col + 2] = v.z + dv.z;
        sA[rr][col + 3] = v.w + dv.w;
    }
    __syncthreads();

    const bool isA = (t < ROWS);
    const int  r   = isA ? t : (t - ROWS);

    float str[MID], sti[MID];   // A: e_j at [j] (j=1..39); B: c_j at [j-MID] (j=40..78)
    float2 X;                   // A: F ratio; B: W ratio

    // ---------------- phase 1: half-recursions, store CF terms ----------------
    if (isA) {
        X = make_float2(sA[r][0], -1.0f);               // F_0 = d_0
        #pragma unroll
        for (int j = 1; j < MID; ++j) {
            float inv  = __builtin_amdgcn_rcpf(X.x * X.x + X.y * X.y);
            float binv = sBC[j - 1] * inv;
            float ex =  binv * X.x;
            float ey = -binv * X.y;
            str[j] = ex; sti[j] = ey;
            X.x = sA[r][j] - ex;                        // F_j
            X.y = -1.0f - ey;
        }
        sFb[r] = X;                                     // F_{MID-1}
    } else {
        X = make_float2(sA[r][N - 1], -1.0f);           // W_{N-1} = d_{N-1}
        #pragma unroll
        for (int j = N - 2; j >= MID; --j) {
            float inv  = __builtin_amdgcn_rcpf(X.x * X.x + X.y * X.y);
            float binv = sBC[j] * inv;
            float cx =  binv * X.x;
            float cy = -binv * X.y;
            str[j - MID] = cx; sti[j - MID] = cy;
            X.x = sA[r][j] - cx;                        // W_j
            X.y = -1.0f - cy;
        }
        sWb[r] = X;                                     // W_MID
    }
    __syncthreads();

    X = isA ? sWb[r] : sFb[r];   // A continues backward from W_MID; B forward from F_{MID-1}

    // ---------------- phase 2: finish opposite recursion + emit G ----------------
    #pragma unroll
    for (int b8 = 0; b8 < 5; ++b8) {
        if (isA) {
            #pragma unroll
            for (int u = 0; u < 8; ++u) {
                const int j = MID - 1 - (b8 * 8 + u);    // 39..0
                float inv  = __builtin_amdgcn_rcpf(X.x * X.x + X.y * X.y);
                float binv = sBC[j] * inv;
                float cx =  binv * X.x;                  // c_j = bc_j / W_{j+1}
                float cy = -binv * X.y;
                float a  = sA[r][j];
                float Wx = a - cx;                       // W_j
                float Wy = -1.0f - cy;
                float ex = (j >= 1) ? str[j] : 0.0f;
                float ey = (j >= 1) ? sti[j] : 0.0f;
                float zx = Wx - ex;                      // 1/G_j
                float zy = Wy - ey;
                float gi = __builtin_amdgcn_rcpf(zx * zx + zy * zy);
                sO[r][j & 7] = make_float2(zx * gi, -zy * gi);
                X.x = Wx; X.y = Wy;
            }
        } else {
            #pragma unroll
            for (int u = 0; u < 8; ++u) {
                const int j = MID + b8 * 8 + u;          // 40..79
                float inv  = __builtin_amdgcn_rcpf(X.x * X.x + X.y * X.y);
                float binv = sBC[j - 1] * inv;
                float ex =  binv * X.x;                  // e_j = bc_{j-1}/F_{j-1}
                float ey = -binv * X.y;
                float a  = sA[r][j];
                float Fx = a - ex;                       // F_j
                float Fy = -1.0f - ey;
                float cx = (j < N - 1) ? str[j - MID] : 0.0f;
                float cy = (j < N - 1) ? sti[j - MID] : 0.0f;
                float zx = Fx - cx;                      // 1/G_j
                float zy = Fy - cy;
                float gi = __builtin_amdgcn_rcpf(zx * zx + zy * zy);
                sO[r][8 + (j & 7)] = make_float2(zx * gi, -zy * gi);
                X.x = Fx; X.y = Fy;
            }
        }
        __syncthreads();
        // flush both 8-col chunks, coalesced float4 (64B-line aligned)
        {
            const int cA0 = MID - 8 - 8 * b8;            // 32,24,16,8,0
            const int cB0 = MID + 8 * b8;                // 40,48,56,64,72
            #pragma unroll
            for (int i = 0; i < 2; ++i) {
                int idx = i * 128 + t;                   // f4 unit
                int rr  = idx >> 2;
                int c2  = (idx & 3) << 1;
                float2 g0 = sO[rr][c2];
                float2 g1 = sO[rr][c2 + 1];
                *(float4*)(otile + (size_t)rr * N + cA0 + c2) =
                    make_float4(g0.x, g0.y, g1.x, g1.y);
                float2 h0v = sO[rr][8 + c2];
                float2 h1v = sO[rr][9 + c2];
                *(float4*)(otile + (size_t)rr * N + cB0 + c2) =
                    make_float4(h0v.x, h0v.y, h1v.x, h1v.y);
            }
        }
        __syncthreads();
    }
}

// ================= generic fallback (round-1 kernel, any N) ==================
__global__ __launch_bounds__(256) void greens_generic(
    const float* __restrict__ he,
    const float* __restrict__ h0d,
    const float* __restrict__ h0sub,
    const float* __restrict__ h0sup,
    float2* __restrict__ out,
    int Bn, int N)
{
    __shared__ float sa[MAXN];
    __shared__ float sbc[MAXN];
    const int t = threadIdx.x;
    if (t < N)     sa[t]  = h0d[t];
    if (t < N - 1) sbc[t] = h0sub[t] * h0sup[t];
    __syncthreads();

    const int b = blockIdx.x * blockDim.x + t;
    if (b >= Bn) return;

    const float* __restrict__ row  = he  + (size_t)b * N;
    float2*      __restrict__ orow = out + (size_t)b * N;

    double tpr = 1.0, tpi = 0.0;
    double tcr = (double)sa[0] + (double)row[0];
    double tci = -1.0;
    orow[0] = make_float2(1.0f, 0.0f);
    for (int k = 1; k < N; ++k) {
        orow[k] = make_float2((float)tcr, (float)tci);
        double ak = (double)sa[k] + (double)row[k];
        double bk = (double)sbc[k - 1];
        double nr = fma(ak, tcr,  tci) - bk * tpr;
        double ni = fma(ak, tci, -tcr) - bk * tpi;
        tpr = tcr; tpi = tci; tcr = nr; tci = ni;
    }
    const double dr = tcr, di = tci;
    const double inv = 1.0 / (dr * dr + di * di);
    const double cr  =  dr * inv;
    const double ci_ = -di * inv;

    double f1r = 1.0, f1i = 0.0;
    double f2r = 0.0, f2i = 0.0;
    for (int j = N - 1; j >= 0; --j) {
        float2 thv = orow[j];
        double tr = (double)thv.x, ti = (double)thv.y;
        double nr = tr * f1r - ti * f1i;
        double ni = tr * f1i + ti * f1r;
        orow[j] = make_float2((float)(nr * cr - ni * ci_),
                              (float)(nr * ci_ + ni * cr));
        double aj = (double)sa[j] + (double)row[j];
        double bj = (j < N - 1) ? (double)sbc[j] : 0.0;
        double pr = fma(aj, f1r,  f1i) - bj * f2r;
        double pi = fma(aj, f1i, -f1r) - bj * f2i;
        f2r = f1r; f2i = f1i; f1r = pr; f1i = pi;
    }
}

extern "C" void kernel_launch(void* const* d_in, const int* in_sizes, int n_in,
                              void* d_out, int out_size, void* d_ws, size_t ws_size,
                              hipStream_t stream) {
    const float* he    = (const float*)d_in[0];
    const float* h0d   = (const float*)d_in[1];
    const float* h0sub = (const float*)d_in[2];
    const float* h0sup = (const float*)d_in[3];
    const int N  = in_sizes[1];           // 80
    const int Bn = in_sizes[0] / N;       // 131072
    float2* out = (float2*)d_out;

    if (N == 80 && (Bn % 64) == 0) {
        const int grid = Bn / 64;
        hipLaunchKernelGGL((greens_cf<80>), dim3(grid), dim3(128), 0, stream,
                           he, h0d, h0sub, h0sup, out);
    } else {
        const int block = 256;
        const int grid  = (Bn + block - 1) / block;
        hipLaunchKernelGGL(greens_generic, dim3(grid), dim3(block), 0, stream,
                           he, h0d, h0sub, h0sup, out, Bn, N);
    }
}

// Round 4
// 126.293 us; speedup vs baseline: 3.8734x; 1.0081x over previous
//
#include <hip/hip_runtime.h>

#define MAXN 128

// ===== continued-fraction kernel: single-wave blocks, 2 lanes/row, fp32 ======
// 1/G_j = d_j - e_j - c_j,  e_j = bc_{j-1}/F_{j-1},  c_j = bc_j/W_{j+1}
// F_j = d_j - e_j (ratio theta_{j+1}/theta_j), W_j = d_j - c_j (phi_j/phi_{j+1})
// Im(F),Im(W) <= -1 always => O(1) magnitudes, fp32 + v_rcp stable.
// Lanes 0-31 (A) run forward on rows 0-31; lanes 32-63 (B) run backward on the
// same rows. Handoff F_39 <-> W_40 via shfl_xor(32). Branchless direction via
// lane-selected indices. No __syncthreads in the main loop (wave-synchronous).
template<int N>
__global__ __launch_bounds__(64, 4) void greens_cf1w(
    const float* __restrict__ he,    // (B, N)
    const float* __restrict__ h0d,   // (N)
    const float* __restrict__ h0sub, // (N-1)
    const float* __restrict__ h0sup, // (N-1)
    float2* __restrict__ out)        // (B, N)
{
    constexpr int ROWS = 32;
    constexpr int MID  = N / 2;      // 40
    static_assert(N == 80, "tuned for N=80");

    __shared__ float  sA[ROWS][N + 1];   // a = h0d + he; pad 81 -> 2-way-free reads
    __shared__ float2 sO[ROWS][17];      // out staging: slots 0-7 A-chunk, 8-15 B-chunk
    __shared__ float  sBC[N];            // bc_j, j=0..N-2

    const int t = threadIdx.x;
    if (t < N - 1)      sBC[t]      = h0sub[t] * h0sup[t];
    if (t + 64 < N - 1) sBC[t + 64] = h0sub[t + 64] * h0sup[t + 64];

    const int row0 = blockIdx.x * ROWS;
    const float* __restrict__ tile  = he  + (size_t)row0 * N;
    float2*      __restrict__ otile = out + (size_t)row0 * N;

    // ---- stage a-tile, coalesced float4 (64 lanes x 16B = 1KB/instr) ----
    #pragma unroll
    for (int i = 0; i < (ROWS * N / 4) / 64; ++i) {   // 10 iters
        int idx = i * 64 + t;
        int rr  = idx / (N / 4);
        int q   = idx - rr * (N / 4);
        int col = q * 4;
        float4 v  = *(const float4*)(tile + (size_t)rr * N + col);
        float4 dv = *(const float4*)(h0d + col);
        sA[rr][col + 0] = v.x + dv.x;
        sA[rr][col + 1] = v.y + dv.y;
        sA[rr][col + 2] = v.z + dv.z;
        sA[rr][col + 3] = v.w + dv.w;
    }
    __syncthreads();   // single-wave block: cheap; nothing global pending

    const int  r   = t & 31;
    const bool isA = (t < 32);

    float str_[MID - 1], sti_[MID - 1];   // 39 stored CF terms (e_j / c_j)
    float2 X;
    X = make_float2(sA[r][isA ? 0 : (N - 1)], -1.0f);   // F_0 = d_0 / W_{N-1} = d_{N-1}

    // ---- phase 1: 39 steps, store e_{s+1} (A) / c_{78-s} (B) at [s] ----
    #pragma unroll
    for (int s = 0; s < MID - 1; ++s) {
        int col = isA ? (s + 1) : (N - 2 - s);          // d-index being consumed
        int bci = isA ? s : (N - 2 - s);                // bc-index
        float inv  = __builtin_amdgcn_rcpf(X.x * X.x + X.y * X.y);
        float binv = sBC[bci] * inv;
        float ex =  binv * X.x;
        float ey = -binv * X.y;
        str_[s] = ex; sti_[s] = ey;
        X.x = sA[r][col] - ex;                          // F_{s+1} / W_{78-s}
        X.y = -1.0f - ey;
    }

    // ---- handoff: A gets W_40, B gets F_39 (in-wave, no barrier) ----
    X.x = __shfl_xor(X.x, 32);
    X.y = __shfl_xor(X.y, 32);

    // ---- phase 2: finish opposite recursion, emit G, flush every 8 cols ----
    #pragma unroll
    for (int b8 = 0; b8 < 5; ++b8) {
        #pragma unroll
        for (int u = 0; u < 8; ++u) {
            const int u2  = b8 * 8 + u;
            const int j   = isA ? (MID - 1 - u2) : (MID + u2);   // 39..0 / 40..79
            const int bci = isA ? (MID - 1 - u2) : (MID - 1 + u2);
            float inv  = __builtin_amdgcn_rcpf(X.x * X.x + X.y * X.y);
            float binv = sBC[bci] * inv;
            float tx =  binv * X.x;                     // c_j (A) / e_j (B)
            float ty = -binv * X.y;
            float a  = sA[r][j];
            float Xx = a - tx;                          // W_j (A) / F_j (B)
            float Xy = -1.0f - ty;
            float ox = (u2 < MID - 1) ? str_[MID - 2 - u2] : 0.0f;
            float oy = (u2 < MID - 1) ? sti_[MID - 2 - u2] : 0.0f;
            float zx = Xx - ox;                         // 1/G_j
            float zy = Xy - oy;
            float gi = __builtin_amdgcn_rcpf(zx * zx + zy * zy);
            const int slot = isA ? (j & 7) : (8 + (j & 7));
            sO[r][slot] = make_float2(zx * gi, -zy * gi);
            X.x = Xx; X.y = Xy;
        }
        // wave-synchronous flush: 2 full 64B lines per 8-lane group, no barrier
        #pragma unroll
        for (int i = 0; i < 4; ++i) {
            int idx = i * 64 + t;
            int rr  = idx >> 3;
            int u   = idx & 7;
            int col = (u < 4) ? (MID - 8 - 8 * b8 + 2 * u)    // A chunk: 32-8*b8 ..
                              : (MID - 8 + 8 * b8 + 2 * u);   // B chunk: 40+8*b8 ..
            float2 g0 = sO[rr][2 * u];
            float2 g1 = sO[rr][2 * u + 1];
            *(float4*)(otile + (size_t)rr * N + col) =
                make_float4(g0.x, g0.y, g1.x, g1.y);
        }
    }
}

// ================= generic fallback (round-1 kernel, any N) ==================
__global__ __launch_bounds__(256) void greens_generic(
    const float* __restrict__ he,
    const float* __restrict__ h0d,
    const float* __restrict__ h0sub,
    const float* __restrict__ h0sup,
    float2* __restrict__ out,
    int Bn, int N)
{
    __shared__ float sa[MAXN];
    __shared__ float sbc[MAXN];
    const int t = threadIdx.x;
    if (t < N)     sa[t]  = h0d[t];
    if (t < N - 1) sbc[t] = h0sub[t] * h0sup[t];
    __syncthreads();

    const int b = blockIdx.x * blockDim.x + t;
    if (b >= Bn) return;

    const float* __restrict__ row  = he  + (size_t)b * N;
    float2*      __restrict__ orow = out + (size_t)b * N;

    double tpr = 1.0, tpi = 0.0;
    double tcr = (double)sa[0] + (double)row[0];
    double tci = -1.0;
    orow[0] = make_float2(1.0f, 0.0f);
    for (int k = 1; k < N; ++k) {
        orow[k] = make_float2((float)tcr, (float)tci);
        double ak = (double)sa[k] + (double)row[k];
        double bk = (double)sbc[k - 1];
        double nr = fma(ak, tcr,  tci) - bk * tpr;
        double ni = fma(ak, tci, -tcr) - bk * tpi;
        tpr = tcr; tpi = tci; tcr = nr; tci = ni;
    }
    const double dr = tcr, di = tci;
    const double inv = 1.0 / (dr * dr + di * di);
    const double cr  =  dr * inv;
    const double ci_ = -di * inv;

    double f1r = 1.0, f1i = 0.0;
    double f2r = 0.0, f2i = 0.0;
    for (int j = N - 1; j >= 0; --j) {
        float2 thv = orow[j];
        double tr = (double)thv.x, ti = (double)thv.y;
        double nr = tr * f1r - ti * f1i;
        double ni = tr * f1i + ti * f1r;
        orow[j] = make_float2((float)(nr * cr - ni * ci_),
                              (float)(nr * ci_ + ni * cr));
        double aj = (double)sa[j] + (double)row[j];
        double bj = (j < N - 1) ? (double)sbc[j] : 0.0;
        double pr = fma(aj, f1r,  f1i) - bj * f2r;
        double pi = fma(aj, f1i, -f1r) - bj * f2i;
        f2r = f1r; f2i = f1i; f1r = pr; f1i = pi;
    }
}

extern "C" void kernel_launch(void* const* d_in, const int* in_sizes, int n_in,
                              void* d_out, int out_size, void* d_ws, size_t ws_size,
                              hipStream_t stream) {
    const float* he    = (const float*)d_in[0];
    const float* h0d   = (const float*)d_in[1];
    const float* h0sub = (const float*)d_in[2];
    const float* h0sup = (const float*)d_in[3];
    const int N  = in_sizes[1];           // 80
    const int Bn = in_sizes[0] / N;       // 131072
    float2* out = (float2*)d_out;

    if (N == 80 && (Bn % 32) == 0) {
        const int grid = Bn / 32;
        hipLaunchKernelGGL((greens_cf1w<80>), dim3(grid), dim3(64), 0, stream,
                           he, h0d, h0sub, h0sup, out);
    } else {
        const int block = 256;
        const int grid  = (Bn + block - 1) / block;
        hipLaunchKernelGGL(greens_generic, dim3(grid), dim3(block), 0, stream,
                           he, h0d, h0sub, h0sup, out, Bn, N);
    }
}